// Round 8
// baseline (291.929 us; speedup 1.0000x reference)
//
#include <hip/hip_runtime.h>

// VQ: z [32,256,32,32] f32, codebook [1024,256] f32
// out: z_q [32,256,32,32] f32 (8388608) then loss scalar f32 (1)
#define NELEM 8388608

typedef __attribute__((ext_vector_type(4))) float f32x4;
typedef unsigned long long ull;

// ---------------------------------------------------------------------------
// prep: codebook -> fp8 e4m3 (scaled x256, exact pow2) in B-fragment-linear
// order for mfma_f32_16x16x32_fp8_fp8, plus exact fp32 norms cn[k], plus
// loss=0 (stream-ordered before vq's atomicAdd).
// frag g = nt*8+ks (512 B): lane L holds cb[nt*16+(L&15)][ks*32+(L>>4)*8+0..7]
__global__ __launch_bounds__(256) void prep_kernel(const float* __restrict__ cb,
                                                   uint2* __restrict__ cbf8,
                                                   float* __restrict__ cn,
                                                   float* __restrict__ loss) {
    const int t = threadIdx.x;
    if (blockIdx.x == 0 && t == 0) *loss = 0.f;
    const int gt = blockIdx.x * 256 + t;          // 0..32767
    const int L = gt & 63, g = gt >> 6;           // frag 0..511
    const int nt = g >> 3, ks = g & 7;
    const int code = nt * 16 + (L & 15);
    const int k0 = ks * 32 + (L >> 4) * 8;
    const float* s = cb + code * 256 + k0;
    float v[8];
    #pragma unroll
    for (int j = 0; j < 8; ++j) v[j] = s[j] * 256.0f;
    int lo = 0, hi = 0;
    lo = __builtin_amdgcn_cvt_pk_fp8_f32(v[0], v[1], lo, false);
    lo = __builtin_amdgcn_cvt_pk_fp8_f32(v[2], v[3], lo, true);
    hi = __builtin_amdgcn_cvt_pk_fp8_f32(v[4], v[5], hi, false);
    hi = __builtin_amdgcn_cvt_pk_fp8_f32(v[6], v[7], hi, true);
    uint2 o; o.x = (unsigned)lo; o.y = (unsigned)hi;
    cbf8[g * 64 + L] = o;

    const int w = t >> 6, lane = t & 63;
    #pragma unroll
    for (int cc = 0; cc < 2; ++cc) {
        int cd = blockIdx.x * 8 + w * 2 + cc;
        float4 qv = *(const float4*)(cb + cd * 256 + lane * 4);
        float s2 = qv.x*qv.x + qv.y*qv.y + qv.z*qv.z + qv.w*qv.w;
        #pragma unroll
        for (int off = 32; off; off >>= 1) s2 += __shfl_down(s2, off, 64);
        if (lane == 0) cn[cd] = s2;
    }
}

// ---------------------------------------------------------------------------
// Fused VQ: grid 1024 x 256 thr. Block = 32 pos; the 4 waves split the 1024
// codes (256 each, 16 tiles of 16). A (32 pos x 256 ch, fp8 x16) register-
// resident per wave; B-frags streamed global->reg with depth-1 double buffer
// (no LDS, no barriers in K-loop). d = (cn+1) - 2*dot > 0 -> float bits
// monotone; key = (bits & ~1023) | code. Cross-wave combine via 32-word LDS,
// then gather fp32 codebook rows, transpose via LDS, write z_q.
// loss = 1.25/NELEM * (sum z^2_exact + sum dmin).
__global__ __launch_bounds__(256, 3) void vq_kernel(
        const float* __restrict__ z, const ull* __restrict__ cbf8,
        const float* __restrict__ cn, const float* __restrict__ cb,
        float* __restrict__ out, float* __restrict__ loss) {
    __shared__ union {
        unsigned wkeys[4][32];
        float Q[32][257];                         // 32.1 KB
    } S;
    __shared__ int codeS[32];
    __shared__ float zsS;

    const int t = threadIdx.x, w = t >> 6, L = t & 63;
    const int col = L & 15, q = L >> 4;
    const int pg = blockIdx.x;
    const int b = pg >> 5, hw0 = (pg & 31) << 5;

    // this wave's 16 code-tiles' norms (+1 bias for positive, bit-monotone d)
    float cnreg[16];
    #pragma unroll
    for (int i = 0; i < 16; ++i) cnreg[i] = cn[w * 256 + i * 16 + col] + 1.0f;

    // A-frags (identical in all 4 waves; block's 32 KB z tile hits L1/L2 on
    // re-read). Exact fp32 z^2 from the same values (wave 0 contributes).
    ull af[2][8];
    float z2 = 0.f;
    const float* zb = z + ((size_t)b << 18) + hw0;
    #pragma unroll
    for (int mf = 0; mf < 2; ++mf) {
        const float* zp = zb + (mf * 16 + col) + ((q * 8) << 10);
        #pragma unroll
        for (int ks = 0; ks < 8; ++ks) {
            const float* sp = zp + ((ks * 32) << 10);
            float v[8];
            #pragma unroll
            for (int j = 0; j < 8; ++j) v[j] = sp[j << 10];
            #pragma unroll
            for (int j = 0; j < 8; ++j) z2 += v[j] * v[j];
            int lo = 0, hi = 0;
            lo = __builtin_amdgcn_cvt_pk_fp8_f32(v[0]*16.f, v[1]*16.f, lo, false);
            lo = __builtin_amdgcn_cvt_pk_fp8_f32(v[2]*16.f, v[3]*16.f, lo, true);
            hi = __builtin_amdgcn_cvt_pk_fp8_f32(v[4]*16.f, v[5]*16.f, hi, false);
            hi = __builtin_amdgcn_cvt_pk_fp8_f32(v[6]*16.f, v[7]*16.f, hi, true);
            af[mf][ks] = ((ull)(unsigned)hi << 32) | (unsigned)lo;
        }
    }

    // wave's private B stream: frags [w*128, w*128+128), lane-linear
    const ull* bp = cbf8 + (size_t)(w * 128) * 64;
    ull B2[2][8];
    #pragma unroll
    for (int ks = 0; ks < 8; ++ks) B2[0][ks] = bp[ks * 64 + L];

    unsigned runmin[2][4];
    #pragma unroll
    for (int r = 0; r < 4; ++r) { runmin[0][r] = 0xFFFFFFFFu; runmin[1][r] = 0xFFFFFFFFu; }

    const float SC = -4.8828125e-4f;              // -2 / (16*256)
    #pragma unroll
    for (int i = 0; i < 16; ++i) {
        const int cur = i & 1;
        if (i < 15) {
            #pragma unroll
            for (int ks = 0; ks < 8; ++ks)
                B2[cur ^ 1][ks] = bp[((i + 1) * 8 + ks) * 64 + L];
        }
        f32x4 a0 = {0,0,0,0}, a1 = {0,0,0,0};
        #pragma unroll
        for (int ks = 0; ks < 8; ++ks) {
            a0 = __builtin_amdgcn_mfma_f32_16x16x32_fp8_fp8(
                     (long long)af[0][ks], (long long)B2[cur][ks], a0, 0, 0, 0);
            a1 = __builtin_amdgcn_mfma_f32_16x16x32_fp8_fp8(
                     (long long)af[1][ks], (long long)B2[cur][ks], a1, 0, 0, 0);
        }
        const unsigned kc = (unsigned)(w * 256 + i * 16 + col);
        #pragma unroll
        for (int r = 0; r < 4; ++r) {
            float d0 = fmaf(SC, a0[r], cnreg[i]);           // ~[0.9,1.1] > 0
            float d1 = fmaf(SC, a1[r], cnreg[i]);
            unsigned k0 = (__float_as_uint(d0) & 0xFFFFFC00u) | kc;
            unsigned k1 = (__float_as_uint(d1) & 0xFFFFFC00u) | kc;
            runmin[0][r] = min(runmin[0][r], k0);
            runmin[1][r] = min(runmin[1][r], k1);
        }
    }

    // per-wave min over its 16 code-columns; pos = mf*16 + q*4 + r
    #pragma unroll
    for (int mf = 0; mf < 2; ++mf)
        #pragma unroll
        for (int r = 0; r < 4; ++r) {
            unsigned v = runmin[mf][r];
            #pragma unroll
            for (int d = 1; d < 16; d <<= 1) v = min(v, (unsigned)__shfl_xor(v, d, 64));
            if (col == 0) S.wkeys[w][mf * 16 + q * 4 + r] = v;
        }

    if (w == 0) {                                 // exact z^2 (once per block)
        float zz = z2;
        #pragma unroll
        for (int off = 32; off; off >>= 1) zz += __shfl_down(zz, off, 64);
        if (L == 0) zsS = zz;
    }
    __syncthreads();

    if (t < 32) {                                 // combine 4 waves, emit loss
        unsigned k0 = min(min(S.wkeys[0][t], S.wkeys[1][t]),
                          min(S.wkeys[2][t], S.wkeys[3][t]));
        codeS[t] = (int)(k0 & 1023u);
        float dmin = __uint_as_float(k0 & 0xFFFFFC00u) - 1.0f;
        #pragma unroll
        for (int d = 1; d < 32; d <<= 1) dmin += __shfl_xor(dmin, d, 64);
        if (t == 0) atomicAdd(loss, (zsS + dmin) * (1.25f / (float)NELEM));
    }
    __syncthreads();                              // wkeys dead -> Q reuse safe

    // gather fp32 codebook rows (coalesced 1 KB/row), transpose via LDS
    #pragma unroll
    for (int rr = 0; rr < 8; ++rr) {
        int row = w * 8 + rr;
        int code = codeS[row];
        float4 v = *(const float4*)(cb + ((size_t)code << 8) + (L << 2));
        float* qp = &S.Q[row][L << 2];
        qp[0] = v.x; qp[1] = v.y; qp[2] = v.z; qp[3] = v.w;
    }
    __syncthreads();
    const size_t obase = ((size_t)b << 18) + hw0;
    const int pgq = L & 7, cidx = L >> 3;
    #pragma unroll
    for (int i = 0; i < 8; ++i) {
        int c = w * 64 + i * 8 + cidx;
        int p0 = pgq * 4;
        float4 qv;
        qv.x = S.Q[p0 + 0][c]; qv.y = S.Q[p0 + 1][c];
        qv.z = S.Q[p0 + 2][c]; qv.w = S.Q[p0 + 3][c];
        *(float4*)(out + obase + ((size_t)c << 10) + p0) = qv;
    }
}

// ---------------------------------------------------------------------------
extern "C" void kernel_launch(void* const* d_in, const int* in_sizes, int n_in,
                              void* d_out, int out_size, void* d_ws, size_t ws_size,
                              hipStream_t stream) {
    const float* z  = (const float*)d_in[0];
    const float* cb = (const float*)d_in[1];
    float* out      = (float*)d_out;
    float* cn       = (float*)d_ws;                           // 4 KB
    uint2* cbf8     = (uint2*)((char*)d_ws + 4096);           // 256 KB
    float* loss     = out + NELEM;

    prep_kernel<<<128, 256, 0, stream>>>(cb, cbf8, cn, loss);
    vq_kernel<<<1024, 256, 0, stream>>>(z, (const ull*)cbf8, cn, cb, out, loss);
}

// Round 9
// 120.208 us; speedup vs baseline: 2.4285x; 2.4285x over previous
//
#include <hip/hip_runtime.h>

// VQ: z [32,256,32,32] f32, codebook [1024,256] f32
// out: z_q [32,256,32,32] f32 (8388608) then loss scalar f32 (1)
#define NELEM 8388608

typedef __attribute__((ext_vector_type(4))) float f32x4;
typedef unsigned long long ull;

// ---------------------------------------------------------------------------
// prep: codebook -> fp8 e4m3 (scaled x256, exact pow2) in B-fragment-linear
// order for mfma_f32_16x16x32_fp8_fp8, plus exact fp32 norms cn[k], plus
// loss=0 (stream-ordered before vq's atomicAdd).
// frag g = nt*8+ks (512 B): lane L holds cb[nt*16+(L&15)][ks*32+(L>>4)*8+0..7]
__global__ __launch_bounds__(256) void prep_kernel(const float* __restrict__ cb,
                                                   uint2* __restrict__ cbf8,
                                                   float* __restrict__ cn,
                                                   float* __restrict__ loss) {
    const int t = threadIdx.x;
    if (blockIdx.x == 0 && t == 0) *loss = 0.f;
    const int gt = blockIdx.x * 256 + t;          // 0..32767
    const int L = gt & 63, g = gt >> 6;           // frag 0..511
    const int nt = g >> 3, ks = g & 7;
    const int code = nt * 16 + (L & 15);
    const int k0 = ks * 32 + (L >> 4) * 8;
    const float* s = cb + code * 256 + k0;
    float v[8];
    #pragma unroll
    for (int j = 0; j < 8; ++j) v[j] = s[j] * 256.0f;
    int lo = 0, hi = 0;
    lo = __builtin_amdgcn_cvt_pk_fp8_f32(v[0], v[1], lo, false);
    lo = __builtin_amdgcn_cvt_pk_fp8_f32(v[2], v[3], lo, true);
    hi = __builtin_amdgcn_cvt_pk_fp8_f32(v[4], v[5], hi, false);
    hi = __builtin_amdgcn_cvt_pk_fp8_f32(v[6], v[7], hi, true);
    uint2 o; o.x = (unsigned)lo; o.y = (unsigned)hi;
    cbf8[g * 64 + L] = o;

    const int w = t >> 6, lane = t & 63;
    #pragma unroll
    for (int cc = 0; cc < 2; ++cc) {
        int cd = blockIdx.x * 8 + w * 2 + cc;
        float4 qv = *(const float4*)(cb + cd * 256 + lane * 4);
        float s2 = qv.x*qv.x + qv.y*qv.y + qv.z*qv.z + qv.w*qv.w;
        #pragma unroll
        for (int off = 32; off; off >>= 1) s2 += __shfl_down(s2, off, 64);
        if (lane == 0) cn[cd] = s2;
    }
}

// ---------------------------------------------------------------------------
// Fused VQ: grid 1024 x 256 thr, 4 blocks/CU. Block = 32 pos; waves split as
// (pos-subtile, codebook-half): wave w -> half = w&1, sub = w>>1; each wave
// 16 pos x 512 codes. A register-resident (af[8]); B streamed global->reg
// from L2 (no LDS, no barriers, no prefetch buffers -> low VGPR, no spill).
// d = (cn+1) - 2*dot > 0 -> float bits monotone; key = (bits&~1023)|code.
// Halves combined via tiny LDS wkeys. loss = 1.25/NELEM*(sum z^2 + sum dmin).
__global__ __launch_bounds__(256, 4) void vq_kernel(
        const float* __restrict__ z, const ull* __restrict__ cbf8,
        const float* __restrict__ cn, const float* __restrict__ cb,
        float* __restrict__ out, float* __restrict__ loss) {
    __shared__ union {
        float cnS[1024];                          // K-loop phase (4 KB)
        float Q[32][257];                         // epilogue (32.9 KB)
    } S;
    __shared__ unsigned wkeys[4][16];
    __shared__ int codeS[32];
    __shared__ float zs[2];

    const int t = threadIdx.x, w = t >> 6, L = t & 63;
    const int col = L & 15, q = L >> 4;
    const int half = w & 1, sub = w >> 1;
    const int pg = blockIdx.x;
    const int b = pg >> 5, hw0 = (pg & 31) << 5;

    // stage cn (+1 bias applied at use: keeps d in ~[0.9,1.1] > 0)
    *(float4*)&S.cnS[t * 4] = *(const float4*)(cn + t * 4);

    // A-frags: pos = hw0 + sub*16 + col, k = ks*32 + q*8 + j. z x16 -> fp8.
    // Exact fp32 z^2 from the same loads (half-0 waves only contribute).
    ull af[8];
    float z2 = 0.f;
    const float* zp = z + ((size_t)b << 18) + hw0 + sub * 16 + col + ((q * 8) << 10);
    #pragma unroll
    for (int ks = 0; ks < 8; ++ks) {
        const float* sp = zp + ((ks * 32) << 10);
        float v[8];
        #pragma unroll
        for (int j = 0; j < 8; ++j) v[j] = sp[j << 10];
        #pragma unroll
        for (int j = 0; j < 8; ++j) z2 += v[j] * v[j];
        int lo = 0, hi = 0;
        lo = __builtin_amdgcn_cvt_pk_fp8_f32(v[0]*16.f, v[1]*16.f, lo, false);
        lo = __builtin_amdgcn_cvt_pk_fp8_f32(v[2]*16.f, v[3]*16.f, lo, true);
        hi = __builtin_amdgcn_cvt_pk_fp8_f32(v[4]*16.f, v[5]*16.f, hi, false);
        hi = __builtin_amdgcn_cvt_pk_fp8_f32(v[6]*16.f, v[7]*16.f, hi, true);
        af[ks] = ((ull)(unsigned)hi << 32) | (unsigned)lo;
    }
    __syncthreads();                              // cnS visible

    unsigned runmin[4];
    #pragma unroll
    for (int r = 0; r < 4; ++r) runmin[r] = 0xFFFFFFFFu;

    const int tb = half * 32;                     // this half's first tile
    const float SC = -4.8828125e-4f;              // -2 / (16*256)

    #pragma unroll 1                              // rolled: keep VGPR low
    for (int i = 0; i < 16; ++i) {
        const ull* p0 = cbf8 + ((size_t)(tb + 2 * i) << 9) + L;   // tile*512
        ull b0[8], b1[8];
        #pragma unroll
        for (int ks = 0; ks < 8; ++ks) b0[ks] = p0[ks * 64];
        #pragma unroll
        for (int ks = 0; ks < 8; ++ks) b1[ks] = p0[512 + ks * 64];
        f32x4 a0 = {0,0,0,0}, a1 = {0,0,0,0};
        #pragma unroll
        for (int ks = 0; ks < 8; ++ks) {          // 2 independent chains
            a0 = __builtin_amdgcn_mfma_f32_16x16x32_fp8_fp8(
                     (long long)af[ks], (long long)b0[ks], a0, 0, 0, 0);
            a1 = __builtin_amdgcn_mfma_f32_16x16x32_fp8_fp8(
                     (long long)af[ks], (long long)b1[ks], a1, 0, 0, 0);
        }
        const int nt0 = tb + 2 * i;
        const float c0 = S.cnS[nt0 * 16 + col] + 1.0f;
        const float c1 = S.cnS[nt0 * 16 + 16 + col] + 1.0f;
        const unsigned kc0 = (unsigned)(nt0 * 16 + col);
        #pragma unroll
        for (int r = 0; r < 4; ++r) {
            float d0 = fmaf(SC, a0[r], c0);
            float d1 = fmaf(SC, a1[r], c1);
            unsigned k0 = (__float_as_uint(d0) & 0xFFFFFC00u) | kc0;
            unsigned k1 = (__float_as_uint(d1) & 0xFFFFFC00u) | (kc0 + 16);
            runmin[r] = min(runmin[r], min(k0, k1));
        }
    }

    // per-wave min over its 16 code-columns; pos-in-subtile = q*4 + r
    #pragma unroll
    for (int r = 0; r < 4; ++r) {
        unsigned v = runmin[r];
        #pragma unroll
        for (int d = 1; d < 16; d <<= 1) v = min(v, (unsigned)__shfl_xor(v, d, 64));
        if (col == 0) wkeys[w][q * 4 + r] = v;
    }
    if (half == 0) {                              // exact z^2 per pos-subtile
        float zz = z2;
        #pragma unroll
        for (int off = 32; off; off >>= 1) zz += __shfl_down(zz, off, 64);
        if (L == 0) zs[sub] = zz;
    }
    __syncthreads();

    if (t < 32) {                                 // combine halves, emit loss
        int s_ = t >> 4;
        unsigned k0 = min(wkeys[2 * s_][t & 15], wkeys[2 * s_ + 1][t & 15]);
        codeS[t] = (int)(k0 & 1023u);
        float dmin = __uint_as_float(k0 & 0xFFFFFC00u) - 1.0f;
        #pragma unroll
        for (int d = 1; d < 32; d <<= 1) dmin += __shfl_xor(dmin, d, 64);
        if (t == 0) atomicAdd(loss, (zs[0] + zs[1] + dmin) * (1.25f / (float)NELEM));
    }
    __syncthreads();                              // cnS dead -> Q reuse safe

    // gather fp32 codebook rows (coalesced 1 KB/row), transpose via LDS
    #pragma unroll
    for (int rr = 0; rr < 8; ++rr) {
        int row = w * 8 + rr;
        int code = codeS[row];
        float4 v = *(const float4*)(cb + ((size_t)code << 8) + (L << 2));
        float* qp = &S.Q[row][L << 2];
        qp[0] = v.x; qp[1] = v.y; qp[2] = v.z; qp[3] = v.w;
    }
    __syncthreads();
    const size_t obase = ((size_t)b << 18) + hw0;
    const int pgq = L & 7, cidx = L >> 3;
    #pragma unroll
    for (int i = 0; i < 8; ++i) {
        int c = w * 64 + i * 8 + cidx;
        int p0 = pgq * 4;
        float4 qv;
        qv.x = S.Q[p0 + 0][c]; qv.y = S.Q[p0 + 1][c];
        qv.z = S.Q[p0 + 2][c]; qv.w = S.Q[p0 + 3][c];
        *(float4*)(out + obase + ((size_t)c << 10) + p0) = qv;
    }
}

// ---------------------------------------------------------------------------
extern "C" void kernel_launch(void* const* d_in, const int* in_sizes, int n_in,
                              void* d_out, int out_size, void* d_ws, size_t ws_size,
                              hipStream_t stream) {
    const float* z  = (const float*)d_in[0];
    const float* cb = (const float*)d_in[1];
    float* out      = (float*)d_out;
    float* cn       = (float*)d_ws;                           // 4 KB
    uint2* cbf8     = (uint2*)((char*)d_ws + 4096);           // 256 KB
    float* loss     = out + NELEM;

    prep_kernel<<<128, 256, 0, stream>>>(cb, cbf8, cn, loss);
    vq_kernel<<<1024, 256, 0, stream>>>(z, (const ull*)cbf8, cn, cb, out, loss);
}